// Round 16
// baseline (705.303 us; speedup 1.0000x reference)
//
#include <hip/hip_runtime.h>

// MambaSkipConnection: B=4, C=192, H=W=64 (L=4096), DI=384, N=16, RK=12, DCONV=4
// Round 16: scan15 fused into scan1 via last-block counter (atomicAdd + fences,
// NO spin-waits -> deadlock-free regardless of dispatch order); scan2 uses
// predicated pq stores instead of mask-fma select. 9 launches.

#define Bn 4
#define Cn 192
#define Hn 64
#define Wn 64
#define Ln 4096
#define DIn 384
#define Nst 16
#define RK 12
#define E2 768
#define NCn 64
#define EPSf 1e-5f
#define HP 66
#define HP2 4356   // 66*66

typedef __bf16 bf16x8 __attribute__((ext_vector_type(8)));
typedef float f32x4 __attribute__((ext_vector_type(4)));
typedef unsigned short u16;
typedef unsigned int u32;

static __device__ __forceinline__ float sigmoidf_(float v) {
    return 1.f / (1.f + __expf(-v));
}
static __device__ __forceinline__ float softplusf_(float v) {
    return v > 15.f ? v : __logf(1.f + __expf(v));
}
static __device__ __forceinline__ u16 f2bf(float f) {
    u32 u = __float_as_uint(f);
    u32 r = (u + 0x7FFFu + ((u >> 16) & 1u)) >> 16;
    return (u16)r;
}
static __device__ __forceinline__ float bf2f(u16 v) {
    return __uint_as_float(((u32)v) << 16);
}
static __device__ __forceinline__ float fexp2(float x) {
#if __has_builtin(__builtin_amdgcn_exp2f)
    return __builtin_amdgcn_exp2f(x);
#else
    return __expf(x * 0.69314718056f);
#endif
}
static __device__ __forceinline__ float quad_sum_dpp(float p) {
    float t, r;
    asm volatile("v_add_f32 %0, %1, %1 quad_perm:[1,0,3,2] row_mask:0xf bank_mask:0xf"
                 : "=&v"(t) : "v"(p));
    asm volatile("v_add_f32 %0, %1, %1 quad_perm:[2,3,0,1] row_mask:0xf bank_mask:0xf"
                 : "=&v"(r) : "v"(t));
    return r;
}
static __device__ __forceinline__ void async16(const u16* g, u16* l) {
    __builtin_amdgcn_global_load_lds((__attribute__((address_space(1))) void*)g,
                                     (__attribute__((address_space(3))) void*)l, 16, 0, 0);
}

// ---------------------------------------------------------------- K0: weight prep + halo-zero + counter-clear
// [0,331776) wcv2 ; [331776,503808) wcomb_bf ; [503808,651264) inpw_bf ;
// [651264,724992) wo_bf ; [724992,725376) scsf ; [725376,750336) t2pad ring ;
// [750336,750432) cnt=0 (96 counters)
__global__ __launch_bounds__(256) void k_prep(const float* __restrict__ rfw,
                                              const float* __restrict__ xpw,
                                              const float* __restrict__ dtw,
                                              const float* __restrict__ inpw,
                                              const float* __restrict__ Wo,
                                              const float* __restrict__ rfb,
                                              const float* __restrict__ bnw,
                                              const float* __restrict__ bnb,
                                              const float* __restrict__ bnm,
                                              const float* __restrict__ bnv,
                                              u16* __restrict__ wcv2,
                                              u16* __restrict__ wcomb_bf,
                                              u16* __restrict__ inpw_bf,
                                              u16* __restrict__ wo_bf,
                                              float* __restrict__ scsf,
                                              u16* __restrict__ t2pad,
                                              u32* __restrict__ cnt) {
    int g = blockIdx.x * 256 + threadIdx.x;
    if (g < 331776) {
        int co = g / 1728;
        int rem = g - co * 1728;
        int tap = rem / Cn, ci = rem - tap * Cn;
        wcv2[g] = f2bf(rfw[((size_t)co * Cn + ci) * 9 + tap]);
    } else if (g < 503808) {
        int i = g - 331776;
        int row = i / 384, k = i - row * 384;
        float v = 0.f;
        if (row < 384) {
#pragma unroll
            for (int r = 0; r < RK; ++r)
                v = fmaf(dtw[row * RK + r], xpw[r * 384 + k], v);
        } else if (row < 416) {
            v = xpw[(RK + row - 384) * 384 + k];
        }
        wcomb_bf[i] = f2bf(v);
    } else if (g < 651264) {
        int i = g - 503808;
        inpw_bf[i] = f2bf(inpw[i]);
    } else if (g < 724992) {
        int i = g - 651264;
        wo_bf[i] = f2bf(Wo[i]);
    } else if (g < 725376) {
        int i = g - 724992;
        if (i < 192) {
            scsf[i] = bnw[i] * rsqrtf(bnv[i] + EPSf);
        } else {
            int c = i - 192;
            float sc = bnw[c] * rsqrtf(bnv[c] + EPSf);
            scsf[i] = (rfb[c] - bnm[c]) * sc + bnb[c];
        }
    } else if (g < 750336) {
        int i = g - 725376;
        int chunk = i % 24;
        int pos = i / 24;
        int b = pos / 260;
        int p = pos - b * 260;
        int cell;
        if (p < 66) cell = p;
        else if (p < 132) cell = 65 * HP + (p - 66);
        else if (p < 196) cell = (p - 132 + 1) * HP;
        else cell = (p - 196 + 1) * HP + 65;
        *(uint4*)&t2pad[((size_t)b * HP2 + cell) * Cn + chunk * 8] = make_uint4(0u, 0u, 0u, 0u);
    } else if (g < 750432) {
        cnt[g - 750336] = 0u;
    }
}

// ---------------------------------------------------------------- K1: LayerNorm -> bf16 tokens
__global__ __launch_bounds__(256) void k_ln(const float* __restrict__ x,
                                            const float* __restrict__ lnw,
                                            const float* __restrict__ lnb,
                                            u16* __restrict__ tn_bf) {
    __shared__ float tile[Cn][65];
    __shared__ float red[2][4][64];
    __shared__ float mean_s[64], rstd_s[64];
    int b = blockIdx.x >> 6;
    int l0 = (blockIdx.x & 63) << 6;
    int tid = threadIdx.x;
    for (int idx = tid; idx < Cn * 64; idx += 256) {
        int c = idx >> 6, ll = idx & 63;
        tile[c][ll] = x[((size_t)(b * Cn + c) << 12) + l0 + ll];
    }
    __syncthreads();
    int ll = tid & 63, grp = tid >> 6;
    float s = 0.f, s2 = 0.f;
    for (int c = grp * 48; c < grp * 48 + 48; ++c) {
        float v = tile[c][ll];
        s += v; s2 += v * v;
    }
    red[0][grp][ll] = s; red[1][grp][ll] = s2;
    __syncthreads();
    if (tid < 64) {
        float m = red[0][0][tid] + red[0][1][tid] + red[0][2][tid] + red[0][3][tid];
        float q = red[1][0][tid] + red[1][1][tid] + red[1][2][tid] + red[1][3][tid];
        m *= (1.f / Cn);
        float var = q * (1.f / Cn) - m * m;
        mean_s[tid] = m;
        rstd_s[tid] = rsqrtf(var + EPSf);
    }
    __syncthreads();
    for (int idx = tid; idx < 64 * Cn; idx += 256) {
        int t = idx / Cn, c = idx - t * Cn;
        float v = (tile[c][t] - mean_s[t]) * rstd_s[t] * lnw[c] + lnb[c];
        tn_bf[(size_t)(b * Ln + l0 + t) * Cn + c] = f2bf(v);
    }
}

// ---------------------------------------------------------------- K2: bf16 GEMM (BM=BN=64, BK=64, async dbuf)
template <int K, int KT, int EPI, int NB, int LDO>
__global__ __launch_bounds__(256) void k_gemm3(const u16* __restrict__ A,
                                               const u16* __restrict__ W,
                                               const float* __restrict__ auxf,
                                               const u16* __restrict__ auxb,
                                               void* __restrict__ out1,
                                               float* __restrict__ out2) {
    __shared__ __align__(16) u16 As[2][64 * 64];
    __shared__ __align__(16) u16 Ws[2][64 * 64];
    int bid = blockIdx.x;
    int q = gridDim.x >> 3;
    int wk = (bid & 7) * q + (bid >> 3);
    int n0 = (wk % NB) << 6;
    int m0 = (wk / NB) << 6;
    int tid = threadIdx.x;
    int wid = tid >> 6, lane = tid & 63;
    int lrow = lane & 15, koct = lane >> 4;
    int sw = lrow & 7;
    int i0 = (wid << 7) + lane;
    int r0 = i0 >> 3, g0 = (i0 & 7) ^ (r0 & 7);
    int i1 = i0 + 64;
    int r1 = i1 >> 3, g1 = (i1 & 7) ^ (r1 & 7);
    const u16* a0p = A + (size_t)(m0 + r0) * K + g0 * 8;
    const u16* a1p = A + (size_t)(m0 + r1) * K + g1 * 8;
    const u16* w0p = W + (size_t)(n0 + r0) * K + g0 * 8;
    const u16* w1p = W + (size_t)(n0 + r1) * K + g1 * 8;
    int lb0 = (wid << 7) << 3;
    int lb1 = lb0 + 512;
    f32x4 acc[4];
#pragma unroll
    for (int j = 0; j < 4; ++j) acc[j] = (f32x4){0.f, 0.f, 0.f, 0.f};

    async16(a0p, &As[0][lb0]); async16(a1p, &As[0][lb1]);
    async16(w0p, &Ws[0][lb0]); async16(w1p, &Ws[0][lb1]);
    __syncthreads();
    for (int kt = 0; kt < KT; ++kt) {
        int cur = kt & 1;
        if (kt + 1 < KT) {
            int kk = (kt + 1) << 6;
            async16(a0p + kk, &As[cur ^ 1][lb0]);
            async16(a1p + kk, &As[cur ^ 1][lb1]);
            async16(w0p + kk, &Ws[cur ^ 1][lb0]);
            async16(w1p + kk, &Ws[cur ^ 1][lb1]);
        }
#pragma unroll
        for (int ks = 0; ks < 2; ++ks) {
            int p8 = (((ks << 2) + koct) ^ sw) << 3;
            bf16x8 a  = *(const bf16x8*)&As[cur][(((wid << 4) + lrow) << 6) + p8];
            bf16x8 b0 = *(const bf16x8*)&Ws[cur][(lrow << 6) + p8];
            bf16x8 b1 = *(const bf16x8*)&Ws[cur][((16 + lrow) << 6) + p8];
            bf16x8 b2 = *(const bf16x8*)&Ws[cur][((32 + lrow) << 6) + p8];
            bf16x8 b3 = *(const bf16x8*)&Ws[cur][((48 + lrow) << 6) + p8];
            acc[0] = __builtin_amdgcn_mfma_f32_16x16x32_bf16(a, b0, acc[0], 0, 0, 0);
            acc[1] = __builtin_amdgcn_mfma_f32_16x16x32_bf16(a, b1, acc[1], 0, 0, 0);
            acc[2] = __builtin_amdgcn_mfma_f32_16x16x32_bf16(a, b2, acc[2], 0, 0, 0);
            acc[3] = __builtin_amdgcn_mfma_f32_16x16x32_bf16(a, b3, acc[3], 0, 0, 0);
        }
        __syncthreads();
    }
    int mrow = m0 + (wid << 4) + (koct << 2);
#pragma unroll
    for (int nf = 0; nf < 4; ++nf) {
        int col = n0 + (nf << 4) + lrow;
        if constexpr (EPI == 0) {
            u16* o = (u16*)out1;
#pragma unroll
            for (int r = 0; r < 4; ++r)
                o[(size_t)(mrow + r) * LDO + col] = f2bf(acc[nf][r]);
        } else if constexpr (EPI == 1) {
            if (col < 384) {
                float dtbc = auxf[col];
                u32* dedux = (u32*)out1;
#pragma unroll
                for (int r = 0; r < 4; ++r) {
                    int m = mrow + r;
                    float de = softplusf_(acc[nf][r] + dtbc);
                    float u = bf2f(auxb[(size_t)m * DIn + col]);
                    dedux[(size_t)m * DIn + col] = (u32)f2bf(de) | ((u32)f2bf(de * u) << 16);
                }
            } else if (col < 416) {
#pragma unroll
                for (int r = 0; r < 4; ++r)
                    out2[(size_t)(mrow + r) * 32 + (col - 384)] = acc[nf][r];
            }
        } else {
            u16* t2 = (u16*)out1;
#pragma unroll
            for (int r = 0; r < 4; ++r) {
                int m = mrow + r;
                int b = m >> 12, l = m & 4095;
                int h = l >> 6, w = l & 63;
                float v = acc[nf][r] + auxf[((size_t)(b * Cn + col) << 12) + l];
                t2[(size_t)(b * HP2 + (h + 1) * HP + (w + 1)) * Cn + col] = f2bf(v);
            }
        }
    }
}

// ---------------------------------------------------------------- K3: causal depthwise conv1d + SiLU
__global__ __launch_bounds__(256) void k_conv1d(const u16* __restrict__ xz,
                                                const float* __restrict__ cw,
                                                const float* __restrict__ cb,
                                                u16* __restrict__ xt_bf) {
    int g = blockIdx.x * 256 + threadIdx.x;
    int m = g / 96, dq = g - m * 96;
    int d = dq << 2;
    int l = m & (Ln - 1);
    float w_[4][4];
    *(float4*)&w_[0][0] = *(const float4*)&cw[(d + 0) << 2];
    *(float4*)&w_[1][0] = *(const float4*)&cw[(d + 1) << 2];
    *(float4*)&w_[2][0] = *(const float4*)&cw[(d + 2) << 2];
    *(float4*)&w_[3][0] = *(const float4*)&cw[(d + 3) << 2];
    float4 bv = *(const float4*)&cb[d];
    float o_[4] = {bv.x, bv.y, bv.z, bv.w};
    const u16* base = xz + (size_t)m * E2 + d;
#pragma unroll
    for (int j = 0; j < 4; ++j) {
        if (l >= j) {
            ushort4 in4 = *(const ushort4*)(base - (size_t)j * E2);
            o_[0] += bf2f(in4.x) * w_[0][3 - j];
            o_[1] += bf2f(in4.y) * w_[1][3 - j];
            o_[2] += bf2f(in4.z) * w_[2][3 - j];
            o_[3] += bf2f(in4.w) * w_[3][3 - j];
        }
    }
    ushort4 rb;
    rb.x = f2bf(o_[0] * sigmoidf_(o_[0]));
    rb.y = f2bf(o_[1] * sigmoidf_(o_[1]));
    rb.z = f2bf(o_[2] * sigmoidf_(o_[2]));
    rb.w = f2bf(o_[3] * sigmoidf_(o_[3]));
    *(ushort4*)&xt_bf[(size_t)m * DIn + d] = rb;
}

// ---------------------------------------------------------------- K6a: scan pass 1 + fused pass 1.5 (last-block)
__global__ __launch_bounds__(256) void k_scan1(const u32* __restrict__ dedux,
                                               const float* __restrict__ bc,
                                               const float* __restrict__ alog,
                                               float* __restrict__ chunkA,
                                               float* __restrict__ chunkH,
                                               u32* __restrict__ cnt,
                                               float* __restrict__ hstart) {
    __shared__ __align__(16) float ds_de[2][16][20], ds_dux[2][16][20], ds_bt[2][16][20];
    __shared__ u32 lastflag;
    int dg = blockIdx.x, c = blockIdx.y, b = blockIdx.z;
    int tid = threadIdx.x;
    int dl = tid >> 4, n = tid & 15;
    int trow = dl, dd = n;
    float Av2 = -__expf(alog[(dg * 16 + dl) * Nst + n]) * 1.44269504f;
    float h = 0.f, sde = 0.f;
    int row0 = b * Ln + c * 64 + trow;
    u32 vN = dedux[(size_t)row0 * DIn + dg * 16 + dd];
    float bN = bc[(size_t)row0 * 32 + dd];
    for (int sub = 0; sub < 4; ++sub) {
        int bs = sub & 1;
        ds_de[bs][dd][trow] = bf2f((u16)(vN & 0xffffu));
        ds_dux[bs][dd][trow] = bf2f((u16)(vN >> 16));
        ds_bt[bs][dd][trow] = bN;
        __syncthreads();
        if (sub < 3) {
            int row = row0 + (sub + 1) * 16;
            vN = dedux[(size_t)row * DIn + dg * 16 + dd];
            bN = bc[(size_t)row * 32 + dd];
        }
#pragma unroll
        for (int t4 = 0; t4 < 4; ++t4) {
            f32x4 de4 = *(const f32x4*)&ds_de[bs][dl][t4 * 4];
            f32x4 dux4 = *(const f32x4*)&ds_dux[bs][dl][t4 * 4];
            f32x4 bb4 = *(const f32x4*)&ds_bt[bs][n][t4 * 4];
#pragma unroll
            for (int j = 0; j < 4; ++j) {
                float a = fexp2(de4[j] * Av2);
                sde += de4[j];
                h = fmaf(a, h, dux4[j] * bb4[j]);
            }
        }
        __syncthreads();
    }
    size_t base = (size_t)(b * NCn + c) * (DIn * Nst) + dg * 256;
    chunkA[base + tid] = fexp2(Av2 * sde);
    chunkH[base + tid] = h;
    // last-block-per-(b,dg) performs the serial chunk scan (no waiting: whichever
    // block arrives last does it; fences give release/acquire visibility).
    __threadfence();
    if (tid == 0) {
        u32 old = atomicAdd(&cnt[b * 24 + dg], 1u);
        lastflag = (old == NCn - 1) ? 1u : 0u;
    }
    __syncthreads();
    if (lastflag) {
        __threadfence();
        size_t off = (size_t)b * NCn * (DIn * Nst) + dg * 256 + tid;
        float hh = 0.f;
        for (int c0 = 0; c0 < NCn; c0 += 8) {
            float Ar[8], Hr[8];
#pragma unroll
            for (int j = 0; j < 8; ++j) {
                Ar[j] = chunkA[off + (size_t)(c0 + j) * (DIn * Nst)];
                Hr[j] = chunkH[off + (size_t)(c0 + j) * (DIn * Nst)];
            }
#pragma unroll
            for (int j = 0; j < 8; ++j) {
                hstart[off + (size_t)(c0 + j) * (DIn * Nst)] = hh;
                hh = fmaf(Ar[j], hh, Hr[j]);
            }
        }
    }
}

// ---------------------------------------------------------------- K6c: scan pass 2 (predicated pq store)
__global__ __launch_bounds__(256) void k_scan2(const u32* __restrict__ dedux,
                                               const float* __restrict__ bc,
                                               const float* __restrict__ alog,
                                               const float* __restrict__ hstart,
                                               const u16* __restrict__ xt_bf,
                                               const u16* __restrict__ xz,
                                               const float* __restrict__ Dp,
                                               u16* __restrict__ agate) {
    __shared__ __align__(16) float ds_de[2][16][20], ds_dux[2][16][20];
    __shared__ __align__(16) float ds_bt[2][16][20], ds_ct[2][16][20];
    __shared__ __align__(16) float pq[2][16][16][4];
    int dg = blockIdx.x, c = blockIdx.y, b = blockIdx.z;
    int tid = threadIdx.x;
    int dl = tid >> 4, n = tid & 15;
    int trow = dl, dd = n;
    int aq = n >> 2, bq = n & 3;
    float Av2 = -__expf(alog[(dg * 16 + dl) * Nst + n]) * 1.44269504f;
    float Dr = Dp[dg * 16 + dd];
    size_t base = (size_t)(b * NCn + c) * (DIn * Nst) + dg * 256;
    float h = hstart[base + tid];
    int row0 = b * Ln + c * 64 + trow;
    int dgoff = dg * 16 + dd;
    u32 vN = dedux[(size_t)row0 * DIn + dgoff];
    float bN = bc[(size_t)row0 * 32 + dd];
    float cN = bc[(size_t)row0 * 32 + 16 + dd];
    u16 uN = xt_bf[(size_t)row0 * DIn + dgoff];
    u16 zN = xz[(size_t)row0 * E2 + DIn + dgoff];
    float pu = 0.f, pz = 0.f;
    int prow = row0;
    for (int sub = 0; sub < 4; ++sub) {
        int bs = sub & 1;
        int row = row0 + sub * 16;
        ds_de[bs][dd][trow] = bf2f((u16)(vN & 0xffffu));
        ds_dux[bs][dd][trow] = bf2f((u16)(vN >> 16));
        ds_bt[bs][dd][trow] = bN;
        ds_ct[bs][dd][trow] = cN;
        float uu = bf2f(uN), zz = bf2f(zN);
        __syncthreads();
        if (sub < 3) {
            int rown = row0 + (sub + 1) * 16;
            vN = dedux[(size_t)rown * DIn + dgoff];
            bN = bc[(size_t)rown * 32 + dd];
            cN = bc[(size_t)rown * 32 + 16 + dd];
            uN = xt_bf[(size_t)rown * DIn + dgoff];
            zN = xz[(size_t)rown * E2 + DIn + dgoff];
        }
        if (sub > 0) {
            f32x4 p4 = *(const f32x4*)&pq[bs ^ 1][trow][dd][0];
            float y = (p4[0] + p4[1]) + (p4[2] + p4[3]);
            float ga = (y + pu * Dr) * (pz * sigmoidf_(pz));
            agate[(size_t)prow * DIn + dgoff] = f2bf(ga);
        }
#pragma unroll
        for (int t4 = 0; t4 < 4; ++t4) {
            f32x4 de4 = *(const f32x4*)&ds_de[bs][dl][t4 * 4];
            f32x4 dux4 = *(const f32x4*)&ds_dux[bs][dl][t4 * 4];
            f32x4 bb4 = *(const f32x4*)&ds_bt[bs][n][t4 * 4];
            f32x4 ct4 = *(const f32x4*)&ds_ct[bs][n][t4 * 4];
#pragma unroll
            for (int j = 0; j < 4; ++j) {
                float a = fexp2(de4[j] * Av2);
                h = fmaf(a, h, dux4[j] * bb4[j]);
                float p = quad_sum_dpp(h * ct4[j]);
                if (bq == j) pq[bs][t4 * 4 + j][dl][aq] = p;  // predicated store (lane bq==j)
            }
        }
        pu = uu; pz = zz; prow = row;
    }
    __syncthreads();
    {
        f32x4 p4 = *(const f32x4*)&pq[1][trow][dd][0];
        float y = (p4[0] + p4[1]) + (p4[2] + p4[3]);
        float ga = (y + pu * Dr) * (pz * sigmoidf_(pz));
        agate[(size_t)prow * DIn + dgoff] = f2bf(ga);
    }
}

// ---------------------------------------------------------------- K8: conv3x3 as padded implicit GEMM (K=1728)
__global__ __launch_bounds__(256) void k_conv3g(const u16* __restrict__ t2pad,
                                                const u16* __restrict__ wcv2,
                                                const float* __restrict__ scsf,
                                                float* __restrict__ out) {
    __shared__ __align__(16) u16 As[2][64 * 64];
    __shared__ __align__(16) u16 Ws[2][64 * 64];
    int bid = blockIdx.x;
    int q = gridDim.x >> 3;
    int wk = (bid & 7) * q + (bid >> 3);
    int n0 = (wk % 3) << 6;
    int rowid = wk / 3;
    int b = rowid >> 6, h = rowid & 63;
    int tid = threadIdx.x;
    int wid = tid >> 6, lane = tid & 63;
    int lrow = lane & 15, koct = lane >> 4;
    int sw = lrow & 7;
    int i0 = (wid << 7) + lane;
    int r0 = i0 >> 3, g0 = (i0 & 7) ^ (r0 & 7);
    int i1 = i0 + 64;
    int r1 = i1 >> 3, g1 = (i1 & 7) ^ (r1 & 7);
    const u16* Abase = t2pad + (size_t)(b * HP2 + (h + 1) * HP + 1) * Cn;
    const u16* a0p = Abase + r0 * Cn + g0 * 8;
    const u16* a1p = Abase + r1 * Cn + g1 * 8;
    const u16* w0p = wcv2 + (size_t)(n0 + r0) * 1728 + g0 * 8;
    const u16* w1p = wcv2 + (size_t)(n0 + r1) * 1728 + g1 * 8;
    int lb0 = (wid << 7) << 3;
    int lb1 = lb0 + 512;
    const int tapoff[9] = {-HP - 1, -HP, -HP + 1, -1, 0, 1, HP - 1, HP, HP + 1};
    f32x4 acc[4];
#pragma unroll
    for (int j = 0; j < 4; ++j) acc[j] = (f32x4){0.f, 0.f, 0.f, 0.f};

    {
        int koff = tapoff[0] * Cn;
        async16(a0p + koff, &As[0][lb0]); async16(a1p + koff, &As[0][lb1]);
        async16(w0p, &Ws[0][lb0]); async16(w1p, &Ws[0][lb1]);
    }
    __syncthreads();
    for (int kt = 0; kt < 27; ++kt) {
        int cur = kt & 1;
        if (kt + 1 < 27) {
            int t = (kt + 1) / 3;
            int koff = tapoff[t] * Cn + (((kt + 1) - t * 3) << 6);
            async16(a0p + koff, &As[cur ^ 1][lb0]);
            async16(a1p + koff, &As[cur ^ 1][lb1]);
            int kw = (kt + 1) << 6;
            async16(w0p + kw, &Ws[cur ^ 1][lb0]);
            async16(w1p + kw, &Ws[cur ^ 1][lb1]);
        }
#pragma unroll
        for (int ks = 0; ks < 2; ++ks) {
            int p8 = (((ks << 2) + koct) ^ sw) << 3;
            bf16x8 a  = *(const bf16x8*)&As[cur][(((wid << 4) + lrow) << 6) + p8];
            bf16x8 b0 = *(const bf16x8*)&Ws[cur][(lrow << 6) + p8];
            bf16x8 b1 = *(const bf16x8*)&Ws[cur][((16 + lrow) << 6) + p8];
            bf16x8 b2 = *(const bf16x8*)&Ws[cur][((32 + lrow) << 6) + p8];
            bf16x8 b3 = *(const bf16x8*)&Ws[cur][((48 + lrow) << 6) + p8];
            acc[0] = __builtin_amdgcn_mfma_f32_16x16x32_bf16(a, b0, acc[0], 0, 0, 0);
            acc[1] = __builtin_amdgcn_mfma_f32_16x16x32_bf16(a, b1, acc[1], 0, 0, 0);
            acc[2] = __builtin_amdgcn_mfma_f32_16x16x32_bf16(a, b2, acc[2], 0, 0, 0);
            acc[3] = __builtin_amdgcn_mfma_f32_16x16x32_bf16(a, b3, acc[3], 0, 0, 0);
        }
        __syncthreads();
    }
    int w0_ = (wid << 4) + (koct << 2);
#pragma unroll
    for (int nf = 0; nf < 4; ++nf) {
        int col = n0 + (nf << 4) + lrow;
        float sc = scsf[col], sf = scsf[192 + col];
        float4 o;
        o.x = fmaxf(acc[nf][0] * sc + sf, 0.f);
        o.y = fmaxf(acc[nf][1] * sc + sf, 0.f);
        o.z = fmaxf(acc[nf][2] * sc + sf, 0.f);
        o.w = fmaxf(acc[nf][3] * sc + sf, 0.f);
        *(float4*)&out[((size_t)(b * Cn + col) << 12) + (h << 6) + w0_] = o;
    }
}

// ----------------------------------------------------------------
extern "C" void kernel_launch(void* const* d_in, const int* in_sizes, int n_in,
                              void* d_out, int out_size, void* d_ws, size_t ws_size,
                              hipStream_t stream) {
    const float* x    = (const float*)d_in[0];
    const float* lnw  = (const float*)d_in[1];
    const float* lnb  = (const float*)d_in[2];
    const float* inpw = (const float*)d_in[3];
    const float* cw   = (const float*)d_in[4];
    const float* cb   = (const float*)d_in[5];
    const float* xpw  = (const float*)d_in[6];
    const float* dtw  = (const float*)d_in[7];
    const float* dtb  = (const float*)d_in[8];
    const float* alog = (const float*)d_in[9];
    const float* Dp   = (const float*)d_in[10];
    const float* Wo   = (const float*)d_in[11];
    const float* rfw  = (const float*)d_in[12];
    const float* rfb  = (const float*)d_in[13];
    const float* bnw  = (const float*)d_in[14];
    const float* bnb  = (const float*)d_in[15];
    const float* bnm  = (const float*)d_in[16];
    const float* bnv  = (const float*)d_in[17];

    float* ws = (float*)d_ws;
    u16* tn_bf    = (u16*)ws;
    float* hstart = ws + 1572864;
    u16* xz       = (u16*)(ws + 3145728);
    u16* xt_bf    = (u16*)(ws + 9437184);
    u32* dedux    = (u32*)(ws + 12582912);
    float* bc     = ws + 18874368;
    u16* agate    = (u16*)(ws + 19398656);
    float* chunkA = ws + 22544384;
    float* chunkH = ws + 24117248;
    u16* wcv2     = (u16*)(ws + 25690112);
    u16* wcomb_bf = (u16*)(ws + 25856000);
    u16* inpw_bf  = (u16*)(ws + 25942016);
    u16* wo_bf    = (u16*)(ws + 26015744);
    float* scsf   = ws + 26052608;
    u32* cnt      = (u32*)(ws + 26052992);   // 96 u32
    u16* t2pad    = (u16*)(ws + 26053120);

    k_prep<<<2932, 256, 0, stream>>>(rfw, xpw, dtw, inpw, Wo, rfb, bnw, bnb, bnm, bnv,
                                     wcv2, wcomb_bf, inpw_bf, wo_bf, scsf, t2pad, cnt);
    k_ln<<<Bn * (Ln / 64), 256, 0, stream>>>(x, lnw, lnb, tn_bf);
    k_gemm3<Cn, 3, 0, 12, E2><<<(Bn * Ln / 64) * 12, 256, 0, stream>>>(
        tn_bf, inpw_bf, nullptr, nullptr, xz, nullptr);
    k_conv1d<<<(Bn * Ln * (DIn / 4)) / 256, 256, 0, stream>>>(xz, cw, cb, xt_bf);
    k_gemm3<DIn, 6, 1, 7, 0><<<(Bn * Ln / 64) * 7, 256, 0, stream>>>(
        xt_bf, wcomb_bf, dtb, xt_bf, dedux, bc);
    k_scan1<<<dim3(DIn / 16, NCn, Bn), 256, 0, stream>>>(dedux, bc, alog,
                                                         chunkA, chunkH, cnt, hstart);
    k_scan2<<<dim3(DIn / 16, NCn, Bn), 256, 0, stream>>>(dedux, bc, alog, hstart,
                                                         xt_bf, xz, Dp, agate);
    k_gemm3<DIn, 6, 2, 3, Cn><<<(Bn * Ln / 64) * 3, 256, 0, stream>>>(
        agate, wo_bf, x, nullptr, (void*)t2pad, nullptr);
    k_conv3g<<<768, 256, 0, stream>>>(t2pad, wcv2, scsf, (float*)d_out);
}

// Round 17
// 175.726 us; speedup vs baseline: 4.0136x; 4.0136x over previous
//
#include <hip/hip_runtime.h>

// MambaSkipConnection: B=4, C=192, H=W=64 (L=4096), DI=384, N=16, RK=12, DCONV=4
// Round 17: REVERT to round-15 structure (177 us verified; R16's last-block
// counter fusion hit device-fence serialization: 705 us). Kept one safe
// intra-block change: scan2 predicated pq store instead of mask-fma select.

#define Bn 4
#define Cn 192
#define Hn 64
#define Wn 64
#define Ln 4096
#define DIn 384
#define Nst 16
#define RK 12
#define E2 768
#define NCn 64
#define EPSf 1e-5f
#define HP 66
#define HP2 4356   // 66*66

typedef __bf16 bf16x8 __attribute__((ext_vector_type(8)));
typedef float f32x4 __attribute__((ext_vector_type(4)));
typedef unsigned short u16;
typedef unsigned int u32;

static __device__ __forceinline__ float sigmoidf_(float v) {
    return 1.f / (1.f + __expf(-v));
}
static __device__ __forceinline__ float softplusf_(float v) {
    return v > 15.f ? v : __logf(1.f + __expf(v));
}
static __device__ __forceinline__ u16 f2bf(float f) {
    u32 u = __float_as_uint(f);
    u32 r = (u + 0x7FFFu + ((u >> 16) & 1u)) >> 16;
    return (u16)r;
}
static __device__ __forceinline__ float bf2f(u16 v) {
    return __uint_as_float(((u32)v) << 16);
}
static __device__ __forceinline__ float fexp2(float x) {
#if __has_builtin(__builtin_amdgcn_exp2f)
    return __builtin_amdgcn_exp2f(x);
#else
    return __expf(x * 0.69314718056f);
#endif
}
static __device__ __forceinline__ float quad_sum_dpp(float p) {
    float t, r;
    asm volatile("v_add_f32 %0, %1, %1 quad_perm:[1,0,3,2] row_mask:0xf bank_mask:0xf"
                 : "=&v"(t) : "v"(p));
    asm volatile("v_add_f32 %0, %1, %1 quad_perm:[2,3,0,1] row_mask:0xf bank_mask:0xf"
                 : "=&v"(r) : "v"(t));
    return r;
}
static __device__ __forceinline__ void async16(const u16* g, u16* l) {
    __builtin_amdgcn_global_load_lds((__attribute__((address_space(1))) void*)g,
                                     (__attribute__((address_space(3))) void*)l, 16, 0, 0);
}

// ---------------------------------------------------------------- K0: weight prep + halo-zero
__global__ __launch_bounds__(256) void k_prep(const float* __restrict__ rfw,
                                              const float* __restrict__ xpw,
                                              const float* __restrict__ dtw,
                                              const float* __restrict__ inpw,
                                              const float* __restrict__ Wo,
                                              const float* __restrict__ rfb,
                                              const float* __restrict__ bnw,
                                              const float* __restrict__ bnb,
                                              const float* __restrict__ bnm,
                                              const float* __restrict__ bnv,
                                              u16* __restrict__ wcv2,
                                              u16* __restrict__ wcomb_bf,
                                              u16* __restrict__ inpw_bf,
                                              u16* __restrict__ wo_bf,
                                              float* __restrict__ scsf,
                                              u16* __restrict__ t2pad) {
    int g = blockIdx.x * 256 + threadIdx.x;
    if (g < 331776) {
        int co = g / 1728;
        int rem = g - co * 1728;
        int tap = rem / Cn, ci = rem - tap * Cn;
        wcv2[g] = f2bf(rfw[((size_t)co * Cn + ci) * 9 + tap]);
    } else if (g < 503808) {
        int i = g - 331776;
        int row = i / 384, k = i - row * 384;
        float v = 0.f;
        if (row < 384) {
#pragma unroll
            for (int r = 0; r < RK; ++r)
                v = fmaf(dtw[row * RK + r], xpw[r * 384 + k], v);
        } else if (row < 416) {
            v = xpw[(RK + row - 384) * 384 + k];
        }
        wcomb_bf[i] = f2bf(v);
    } else if (g < 651264) {
        int i = g - 503808;
        inpw_bf[i] = f2bf(inpw[i]);
    } else if (g < 724992) {
        int i = g - 651264;
        wo_bf[i] = f2bf(Wo[i]);
    } else if (g < 725376) {
        int i = g - 724992;
        if (i < 192) {
            scsf[i] = bnw[i] * rsqrtf(bnv[i] + EPSf);
        } else {
            int c = i - 192;
            float sc = bnw[c] * rsqrtf(bnv[c] + EPSf);
            scsf[i] = (rfb[c] - bnm[c]) * sc + bnb[c];
        }
    } else if (g < 750336) {
        int i = g - 725376;
        int chunk = i % 24;
        int pos = i / 24;
        int b = pos / 260;
        int p = pos - b * 260;
        int cell;
        if (p < 66) cell = p;
        else if (p < 132) cell = 65 * HP + (p - 66);
        else if (p < 196) cell = (p - 132 + 1) * HP;
        else cell = (p - 196 + 1) * HP + 65;
        *(uint4*)&t2pad[((size_t)b * HP2 + cell) * Cn + chunk * 8] = make_uint4(0u, 0u, 0u, 0u);
    }
}

// ---------------------------------------------------------------- K1: LayerNorm -> bf16 tokens
__global__ __launch_bounds__(256) void k_ln(const float* __restrict__ x,
                                            const float* __restrict__ lnw,
                                            const float* __restrict__ lnb,
                                            u16* __restrict__ tn_bf) {
    __shared__ float tile[Cn][65];
    __shared__ float red[2][4][64];
    __shared__ float mean_s[64], rstd_s[64];
    int b = blockIdx.x >> 6;
    int l0 = (blockIdx.x & 63) << 6;
    int tid = threadIdx.x;
    for (int idx = tid; idx < Cn * 64; idx += 256) {
        int c = idx >> 6, ll = idx & 63;
        tile[c][ll] = x[((size_t)(b * Cn + c) << 12) + l0 + ll];
    }
    __syncthreads();
    int ll = tid & 63, grp = tid >> 6;
    float s = 0.f, s2 = 0.f;
    for (int c = grp * 48; c < grp * 48 + 48; ++c) {
        float v = tile[c][ll];
        s += v; s2 += v * v;
    }
    red[0][grp][ll] = s; red[1][grp][ll] = s2;
    __syncthreads();
    if (tid < 64) {
        float m = red[0][0][tid] + red[0][1][tid] + red[0][2][tid] + red[0][3][tid];
        float q = red[1][0][tid] + red[1][1][tid] + red[1][2][tid] + red[1][3][tid];
        m *= (1.f / Cn);
        float var = q * (1.f / Cn) - m * m;
        mean_s[tid] = m;
        rstd_s[tid] = rsqrtf(var + EPSf);
    }
    __syncthreads();
    for (int idx = tid; idx < 64 * Cn; idx += 256) {
        int t = idx / Cn, c = idx - t * Cn;
        float v = (tile[c][t] - mean_s[t]) * rstd_s[t] * lnw[c] + lnb[c];
        tn_bf[(size_t)(b * Ln + l0 + t) * Cn + c] = f2bf(v);
    }
}

// ---------------------------------------------------------------- K2: bf16 GEMM (BM=BN=64, BK=64, async dbuf)
template <int K, int KT, int EPI, int NB, int LDO>
__global__ __launch_bounds__(256) void k_gemm3(const u16* __restrict__ A,
                                               const u16* __restrict__ W,
                                               const float* __restrict__ auxf,
                                               const u16* __restrict__ auxb,
                                               void* __restrict__ out1,
                                               float* __restrict__ out2) {
    __shared__ __align__(16) u16 As[2][64 * 64];
    __shared__ __align__(16) u16 Ws[2][64 * 64];
    int bid = blockIdx.x;
    int q = gridDim.x >> 3;
    int wk = (bid & 7) * q + (bid >> 3);
    int n0 = (wk % NB) << 6;
    int m0 = (wk / NB) << 6;
    int tid = threadIdx.x;
    int wid = tid >> 6, lane = tid & 63;
    int lrow = lane & 15, koct = lane >> 4;
    int sw = lrow & 7;
    int i0 = (wid << 7) + lane;
    int r0 = i0 >> 3, g0 = (i0 & 7) ^ (r0 & 7);
    int i1 = i0 + 64;
    int r1 = i1 >> 3, g1 = (i1 & 7) ^ (r1 & 7);
    const u16* a0p = A + (size_t)(m0 + r0) * K + g0 * 8;
    const u16* a1p = A + (size_t)(m0 + r1) * K + g1 * 8;
    const u16* w0p = W + (size_t)(n0 + r0) * K + g0 * 8;
    const u16* w1p = W + (size_t)(n0 + r1) * K + g1 * 8;
    int lb0 = (wid << 7) << 3;
    int lb1 = lb0 + 512;
    f32x4 acc[4];
#pragma unroll
    for (int j = 0; j < 4; ++j) acc[j] = (f32x4){0.f, 0.f, 0.f, 0.f};

    async16(a0p, &As[0][lb0]); async16(a1p, &As[0][lb1]);
    async16(w0p, &Ws[0][lb0]); async16(w1p, &Ws[0][lb1]);
    __syncthreads();
    for (int kt = 0; kt < KT; ++kt) {
        int cur = kt & 1;
        if (kt + 1 < KT) {
            int kk = (kt + 1) << 6;
            async16(a0p + kk, &As[cur ^ 1][lb0]);
            async16(a1p + kk, &As[cur ^ 1][lb1]);
            async16(w0p + kk, &Ws[cur ^ 1][lb0]);
            async16(w1p + kk, &Ws[cur ^ 1][lb1]);
        }
#pragma unroll
        for (int ks = 0; ks < 2; ++ks) {
            int p8 = (((ks << 2) + koct) ^ sw) << 3;
            bf16x8 a  = *(const bf16x8*)&As[cur][(((wid << 4) + lrow) << 6) + p8];
            bf16x8 b0 = *(const bf16x8*)&Ws[cur][(lrow << 6) + p8];
            bf16x8 b1 = *(const bf16x8*)&Ws[cur][((16 + lrow) << 6) + p8];
            bf16x8 b2 = *(const bf16x8*)&Ws[cur][((32 + lrow) << 6) + p8];
            bf16x8 b3 = *(const bf16x8*)&Ws[cur][((48 + lrow) << 6) + p8];
            acc[0] = __builtin_amdgcn_mfma_f32_16x16x32_bf16(a, b0, acc[0], 0, 0, 0);
            acc[1] = __builtin_amdgcn_mfma_f32_16x16x32_bf16(a, b1, acc[1], 0, 0, 0);
            acc[2] = __builtin_amdgcn_mfma_f32_16x16x32_bf16(a, b2, acc[2], 0, 0, 0);
            acc[3] = __builtin_amdgcn_mfma_f32_16x16x32_bf16(a, b3, acc[3], 0, 0, 0);
        }
        __syncthreads();
    }
    int mrow = m0 + (wid << 4) + (koct << 2);
#pragma unroll
    for (int nf = 0; nf < 4; ++nf) {
        int col = n0 + (nf << 4) + lrow;
        if constexpr (EPI == 0) {
            u16* o = (u16*)out1;
#pragma unroll
            for (int r = 0; r < 4; ++r)
                o[(size_t)(mrow + r) * LDO + col] = f2bf(acc[nf][r]);
        } else if constexpr (EPI == 1) {
            if (col < 384) {
                float dtbc = auxf[col];
                u32* dedux = (u32*)out1;
#pragma unroll
                for (int r = 0; r < 4; ++r) {
                    int m = mrow + r;
                    float de = softplusf_(acc[nf][r] + dtbc);
                    float u = bf2f(auxb[(size_t)m * DIn + col]);
                    dedux[(size_t)m * DIn + col] = (u32)f2bf(de) | ((u32)f2bf(de * u) << 16);
                }
            } else if (col < 416) {
#pragma unroll
                for (int r = 0; r < 4; ++r)
                    out2[(size_t)(mrow + r) * 32 + (col - 384)] = acc[nf][r];
            }
        } else {
            u16* t2 = (u16*)out1;
#pragma unroll
            for (int r = 0; r < 4; ++r) {
                int m = mrow + r;
                int b = m >> 12, l = m & 4095;
                int h = l >> 6, w = l & 63;
                float v = acc[nf][r] + auxf[((size_t)(b * Cn + col) << 12) + l];
                t2[(size_t)(b * HP2 + (h + 1) * HP + (w + 1)) * Cn + col] = f2bf(v);
            }
        }
    }
}

// ---------------------------------------------------------------- K3: causal depthwise conv1d + SiLU
__global__ __launch_bounds__(256) void k_conv1d(const u16* __restrict__ xz,
                                                const float* __restrict__ cw,
                                                const float* __restrict__ cb,
                                                u16* __restrict__ xt_bf) {
    int g = blockIdx.x * 256 + threadIdx.x;
    int m = g / 96, dq = g - m * 96;
    int d = dq << 2;
    int l = m & (Ln - 1);
    float w_[4][4];
    *(float4*)&w_[0][0] = *(const float4*)&cw[(d + 0) << 2];
    *(float4*)&w_[1][0] = *(const float4*)&cw[(d + 1) << 2];
    *(float4*)&w_[2][0] = *(const float4*)&cw[(d + 2) << 2];
    *(float4*)&w_[3][0] = *(const float4*)&cw[(d + 3) << 2];
    float4 bv = *(const float4*)&cb[d];
    float o_[4] = {bv.x, bv.y, bv.z, bv.w};
    const u16* base = xz + (size_t)m * E2 + d;
#pragma unroll
    for (int j = 0; j < 4; ++j) {
        if (l >= j) {
            ushort4 in4 = *(const ushort4*)(base - (size_t)j * E2);
            o_[0] += bf2f(in4.x) * w_[0][3 - j];
            o_[1] += bf2f(in4.y) * w_[1][3 - j];
            o_[2] += bf2f(in4.z) * w_[2][3 - j];
            o_[3] += bf2f(in4.w) * w_[3][3 - j];
        }
    }
    ushort4 rb;
    rb.x = f2bf(o_[0] * sigmoidf_(o_[0]));
    rb.y = f2bf(o_[1] * sigmoidf_(o_[1]));
    rb.z = f2bf(o_[2] * sigmoidf_(o_[2]));
    rb.w = f2bf(o_[3] * sigmoidf_(o_[3]));
    *(ushort4*)&xt_bf[(size_t)m * DIn + d] = rb;
}

// ---------------------------------------------------------------- K6a: scan pass 1 (1 barrier/sub, LDS ping-pong)
__global__ __launch_bounds__(256) void k_scan1(const u32* __restrict__ dedux,
                                               const float* __restrict__ bc,
                                               const float* __restrict__ alog,
                                               float* __restrict__ chunkA,
                                               float* __restrict__ chunkH) {
    __shared__ __align__(16) float ds_de[2][16][20], ds_dux[2][16][20], ds_bt[2][16][20];
    int dg = blockIdx.x, c = blockIdx.y, b = blockIdx.z;
    int tid = threadIdx.x;
    int dl = tid >> 4, n = tid & 15;
    int trow = dl, dd = n;
    float Av2 = -__expf(alog[(dg * 16 + dl) * Nst + n]) * 1.44269504f;
    float h = 0.f, sde = 0.f;
    int row0 = b * Ln + c * 64 + trow;
    u32 vN = dedux[(size_t)row0 * DIn + dg * 16 + dd];
    float bN = bc[(size_t)row0 * 32 + dd];
    for (int sub = 0; sub < 4; ++sub) {
        int bs = sub & 1;
        ds_de[bs][dd][trow] = bf2f((u16)(vN & 0xffffu));
        ds_dux[bs][dd][trow] = bf2f((u16)(vN >> 16));
        ds_bt[bs][dd][trow] = bN;
        __syncthreads();
        if (sub < 3) {
            int row = row0 + (sub + 1) * 16;
            vN = dedux[(size_t)row * DIn + dg * 16 + dd];
            bN = bc[(size_t)row * 32 + dd];
        }
#pragma unroll
        for (int t4 = 0; t4 < 4; ++t4) {
            f32x4 de4 = *(const f32x4*)&ds_de[bs][dl][t4 * 4];
            f32x4 dux4 = *(const f32x4*)&ds_dux[bs][dl][t4 * 4];
            f32x4 bb4 = *(const f32x4*)&ds_bt[bs][n][t4 * 4];
#pragma unroll
            for (int j = 0; j < 4; ++j) {
                float a = fexp2(de4[j] * Av2);
                sde += de4[j];
                h = fmaf(a, h, dux4[j] * bb4[j]);
            }
        }
    }
    size_t base = (size_t)(b * NCn + c) * (DIn * Nst) + dg * 256;
    chunkA[base + tid] = fexp2(Av2 * sde);
    chunkH[base + tid] = h;
}

// ---------------------------------------------------------------- K6b: scan pass 1.5
__global__ __launch_bounds__(256) void k_scan15(const float* __restrict__ chunkA,
                                                const float* __restrict__ chunkH,
                                                float* __restrict__ hstart) {
    int dg = blockIdx.x, b = blockIdx.y;
    int tid = threadIdx.x;
    size_t off = (size_t)b * NCn * (DIn * Nst) + dg * 256 + tid;
    float h = 0.f;
    for (int c0 = 0; c0 < NCn; c0 += 8) {
        float Ar[8], Hr[8];
#pragma unroll
        for (int j = 0; j < 8; ++j) {
            Ar[j] = chunkA[off + (size_t)(c0 + j) * (DIn * Nst)];
            Hr[j] = chunkH[off + (size_t)(c0 + j) * (DIn * Nst)];
        }
#pragma unroll
        for (int j = 0; j < 8; ++j) {
            hstart[off + (size_t)(c0 + j) * (DIn * Nst)] = h;
            h = fmaf(Ar[j], h, Hr[j]);
        }
    }
}

// ---------------------------------------------------------------- K6c: scan pass 2 (predicated pq store)
__global__ __launch_bounds__(256) void k_scan2(const u32* __restrict__ dedux,
                                               const float* __restrict__ bc,
                                               const float* __restrict__ alog,
                                               const float* __restrict__ hstart,
                                               const u16* __restrict__ xt_bf,
                                               const u16* __restrict__ xz,
                                               const float* __restrict__ Dp,
                                               u16* __restrict__ agate) {
    __shared__ __align__(16) float ds_de[2][16][20], ds_dux[2][16][20];
    __shared__ __align__(16) float ds_bt[2][16][20], ds_ct[2][16][20];
    __shared__ __align__(16) float pq[2][16][16][4];
    int dg = blockIdx.x, c = blockIdx.y, b = blockIdx.z;
    int tid = threadIdx.x;
    int dl = tid >> 4, n = tid & 15;
    int trow = dl, dd = n;
    int aq = n >> 2, bq = n & 3;
    float Av2 = -__expf(alog[(dg * 16 + dl) * Nst + n]) * 1.44269504f;
    float Dr = Dp[dg * 16 + dd];
    size_t base = (size_t)(b * NCn + c) * (DIn * Nst) + dg * 256;
    float h = hstart[base + tid];
    int row0 = b * Ln + c * 64 + trow;
    int dgoff = dg * 16 + dd;
    u32 vN = dedux[(size_t)row0 * DIn + dgoff];
    float bN = bc[(size_t)row0 * 32 + dd];
    float cN = bc[(size_t)row0 * 32 + 16 + dd];
    u16 uN = xt_bf[(size_t)row0 * DIn + dgoff];
    u16 zN = xz[(size_t)row0 * E2 + DIn + dgoff];
    float pu = 0.f, pz = 0.f;
    int prow = row0;
    for (int sub = 0; sub < 4; ++sub) {
        int bs = sub & 1;
        int row = row0 + sub * 16;
        ds_de[bs][dd][trow] = bf2f((u16)(vN & 0xffffu));
        ds_dux[bs][dd][trow] = bf2f((u16)(vN >> 16));
        ds_bt[bs][dd][trow] = bN;
        ds_ct[bs][dd][trow] = cN;
        float uu = bf2f(uN), zz = bf2f(zN);
        __syncthreads();
        if (sub < 3) {
            int rown = row0 + (sub + 1) * 16;
            vN = dedux[(size_t)rown * DIn + dgoff];
            bN = bc[(size_t)rown * 32 + dd];
            cN = bc[(size_t)rown * 32 + 16 + dd];
            uN = xt_bf[(size_t)rown * DIn + dgoff];
            zN = xz[(size_t)rown * E2 + DIn + dgoff];
        }
        if (sub > 0) {
            f32x4 p4 = *(const f32x4*)&pq[bs ^ 1][trow][dd][0];
            float y = (p4[0] + p4[1]) + (p4[2] + p4[3]);
            float ga = (y + pu * Dr) * (pz * sigmoidf_(pz));
            agate[(size_t)prow * DIn + dgoff] = f2bf(ga);
        }
#pragma unroll
        for (int t4 = 0; t4 < 4; ++t4) {
            f32x4 de4 = *(const f32x4*)&ds_de[bs][dl][t4 * 4];
            f32x4 dux4 = *(const f32x4*)&ds_dux[bs][dl][t4 * 4];
            f32x4 bb4 = *(const f32x4*)&ds_bt[bs][n][t4 * 4];
            f32x4 ct4 = *(const f32x4*)&ds_ct[bs][n][t4 * 4];
#pragma unroll
            for (int j = 0; j < 4; ++j) {
                float a = fexp2(de4[j] * Av2);
                h = fmaf(a, h, dux4[j] * bb4[j]);
                float p = quad_sum_dpp(h * ct4[j]);
                if (bq == j) pq[bs][t4 * 4 + j][dl][aq] = p;
            }
        }
        pu = uu; pz = zz; prow = row;
    }
    __syncthreads();
    {
        f32x4 p4 = *(const f32x4*)&pq[1][trow][dd][0];
        float y = (p4[0] + p4[1]) + (p4[2] + p4[3]);
        float ga = (y + pu * Dr) * (pz * sigmoidf_(pz));
        agate[(size_t)prow * DIn + dgoff] = f2bf(ga);
    }
}

// ---------------------------------------------------------------- K8: conv3x3 as padded implicit GEMM (K=1728)
__global__ __launch_bounds__(256) void k_conv3g(const u16* __restrict__ t2pad,
                                                const u16* __restrict__ wcv2,
                                                const float* __restrict__ scsf,
                                                float* __restrict__ out) {
    __shared__ __align__(16) u16 As[2][64 * 64];
    __shared__ __align__(16) u16 Ws[2][64 * 64];
    int bid = blockIdx.x;
    int q = gridDim.x >> 3;
    int wk = (bid & 7) * q + (bid >> 3);
    int n0 = (wk % 3) << 6;
    int rowid = wk / 3;
    int b = rowid >> 6, h = rowid & 63;
    int tid = threadIdx.x;
    int wid = tid >> 6, lane = tid & 63;
    int lrow = lane & 15, koct = lane >> 4;
    int sw = lrow & 7;
    int i0 = (wid << 7) + lane;
    int r0 = i0 >> 3, g0 = (i0 & 7) ^ (r0 & 7);
    int i1 = i0 + 64;
    int r1 = i1 >> 3, g1 = (i1 & 7) ^ (r1 & 7);
    const u16* Abase = t2pad + (size_t)(b * HP2 + (h + 1) * HP + 1) * Cn;
    const u16* a0p = Abase + r0 * Cn + g0 * 8;
    const u16* a1p = Abase + r1 * Cn + g1 * 8;
    const u16* w0p = wcv2 + (size_t)(n0 + r0) * 1728 + g0 * 8;
    const u16* w1p = wcv2 + (size_t)(n0 + r1) * 1728 + g1 * 8;
    int lb0 = (wid << 7) << 3;
    int lb1 = lb0 + 512;
    const int tapoff[9] = {-HP - 1, -HP, -HP + 1, -1, 0, 1, HP - 1, HP, HP + 1};
    f32x4 acc[4];
#pragma unroll
    for (int j = 0; j < 4; ++j) acc[j] = (f32x4){0.f, 0.f, 0.f, 0.f};

    {
        int koff = tapoff[0] * Cn;
        async16(a0p + koff, &As[0][lb0]); async16(a1p + koff, &As[0][lb1]);
        async16(w0p, &Ws[0][lb0]); async16(w1p, &Ws[0][lb1]);
    }
    __syncthreads();
    for (int kt = 0; kt < 27; ++kt) {
        int cur = kt & 1;
        if (kt + 1 < 27) {
            int t = (kt + 1) / 3;
            int koff = tapoff[t] * Cn + (((kt + 1) - t * 3) << 6);
            async16(a0p + koff, &As[cur ^ 1][lb0]);
            async16(a1p + koff, &As[cur ^ 1][lb1]);
            int kw = (kt + 1) << 6;
            async16(w0p + kw, &Ws[cur ^ 1][lb0]);
            async16(w1p + kw, &Ws[cur ^ 1][lb1]);
        }
#pragma unroll
        for (int ks = 0; ks < 2; ++ks) {
            int p8 = (((ks << 2) + koct) ^ sw) << 3;
            bf16x8 a  = *(const bf16x8*)&As[cur][(((wid << 4) + lrow) << 6) + p8];
            bf16x8 b0 = *(const bf16x8*)&Ws[cur][(lrow << 6) + p8];
            bf16x8 b1 = *(const bf16x8*)&Ws[cur][((16 + lrow) << 6) + p8];
            bf16x8 b2 = *(const bf16x8*)&Ws[cur][((32 + lrow) << 6) + p8];
            bf16x8 b3 = *(const bf16x8*)&Ws[cur][((48 + lrow) << 6) + p8];
            acc[0] = __builtin_amdgcn_mfma_f32_16x16x32_bf16(a, b0, acc[0], 0, 0, 0);
            acc[1] = __builtin_amdgcn_mfma_f32_16x16x32_bf16(a, b1, acc[1], 0, 0, 0);
            acc[2] = __builtin_amdgcn_mfma_f32_16x16x32_bf16(a, b2, acc[2], 0, 0, 0);
            acc[3] = __builtin_amdgcn_mfma_f32_16x16x32_bf16(a, b3, acc[3], 0, 0, 0);
        }
        __syncthreads();
    }
    int w0_ = (wid << 4) + (koct << 2);
#pragma unroll
    for (int nf = 0; nf < 4; ++nf) {
        int col = n0 + (nf << 4) + lrow;
        float sc = scsf[col], sf = scsf[192 + col];
        float4 o;
        o.x = fmaxf(acc[nf][0] * sc + sf, 0.f);
        o.y = fmaxf(acc[nf][1] * sc + sf, 0.f);
        o.z = fmaxf(acc[nf][2] * sc + sf, 0.f);
        o.w = fmaxf(acc[nf][3] * sc + sf, 0.f);
        *(float4*)&out[((size_t)(b * Cn + col) << 12) + (h << 6) + w0_] = o;
    }
}

// ----------------------------------------------------------------
extern "C" void kernel_launch(void* const* d_in, const int* in_sizes, int n_in,
                              void* d_out, int out_size, void* d_ws, size_t ws_size,
                              hipStream_t stream) {
    const float* x    = (const float*)d_in[0];
    const float* lnw  = (const float*)d_in[1];
    const float* lnb  = (const float*)d_in[2];
    const float* inpw = (const float*)d_in[3];
    const float* cw   = (const float*)d_in[4];
    const float* cb   = (const float*)d_in[5];
    const float* xpw  = (const float*)d_in[6];
    const float* dtw  = (const float*)d_in[7];
    const float* dtb  = (const float*)d_in[8];
    const float* alog = (const float*)d_in[9];
    const float* Dp   = (const float*)d_in[10];
    const float* Wo   = (const float*)d_in[11];
    const float* rfw  = (const float*)d_in[12];
    const float* rfb  = (const float*)d_in[13];
    const float* bnw  = (const float*)d_in[14];
    const float* bnb  = (const float*)d_in[15];
    const float* bnm  = (const float*)d_in[16];
    const float* bnv  = (const float*)d_in[17];

    float* ws = (float*)d_ws;
    u16* tn_bf    = (u16*)ws;
    float* hstart = ws + 1572864;
    u16* xz       = (u16*)(ws + 3145728);
    u16* xt_bf    = (u16*)(ws + 9437184);
    u32* dedux    = (u32*)(ws + 12582912);
    float* bc     = ws + 18874368;
    u16* agate    = (u16*)(ws + 19398656);
    float* chunkA = ws + 22544384;
    float* chunkH = ws + 24117248;
    u16* wcv2     = (u16*)(ws + 25690112);
    u16* wcomb_bf = (u16*)(ws + 25856000);
    u16* inpw_bf  = (u16*)(ws + 25942016);
    u16* wo_bf    = (u16*)(ws + 26015744);
    float* scsf   = ws + 26052608;
    u16* t2pad    = (u16*)(ws + 26053120);

    k_prep<<<2931, 256, 0, stream>>>(rfw, xpw, dtw, inpw, Wo, rfb, bnw, bnb, bnm, bnv,
                                     wcv2, wcomb_bf, inpw_bf, wo_bf, scsf, t2pad);
    k_ln<<<Bn * (Ln / 64), 256, 0, stream>>>(x, lnw, lnb, tn_bf);
    k_gemm3<Cn, 3, 0, 12, E2><<<(Bn * Ln / 64) * 12, 256, 0, stream>>>(
        tn_bf, inpw_bf, nullptr, nullptr, xz, nullptr);
    k_conv1d<<<(Bn * Ln * (DIn / 4)) / 256, 256, 0, stream>>>(xz, cw, cb, xt_bf);
    k_gemm3<DIn, 6, 1, 7, 0><<<(Bn * Ln / 64) * 7, 256, 0, stream>>>(
        xt_bf, wcomb_bf, dtb, xt_bf, dedux, bc);
    k_scan1<<<dim3(DIn / 16, NCn, Bn), 256, 0, stream>>>(dedux, bc, alog, chunkA, chunkH);
    k_scan15<<<dim3(DIn / 16, Bn), 256, 0, stream>>>(chunkA, chunkH, hstart);
    k_scan2<<<dim3(DIn / 16, NCn, Bn), 256, 0, stream>>>(dedux, bc, alog, hstart,
                                                         xt_bf, xz, Dp, agate);
    k_gemm3<DIn, 6, 2, 3, Cn><<<(Bn * Ln / 64) * 3, 256, 0, stream>>>(
        agate, wo_bf, x, nullptr, (void*)t2pad, nullptr);
    k_conv3g<<<768, 256, 0, stream>>>(t2pad, wcv2, scsf, (float*)d_out);
}